// Round 17
// baseline (9660.619 us; speedup 1.0000x reference)
//
#include <hip/hip_runtime.h>
#include <stdint.h>

#define NN 2048
#define NCORE 8
#define TSIM 32
#define PLANE (256*2048)       // 512 KiB i8 plane

typedef int i4v __attribute__((ext_vector_type(4)));

__device__ __forceinline__ void load_lds16(const void* g, void* l) {
  __builtin_amdgcn_global_load_lds((const __attribute__((address_space(1))) void*)g,
                                   (__attribute__((address_space(3))) void*)l, 16, 0, 0);
}

// ---------------- spike trains, i8 {0,1}, 64B-group 2-bit swizzle ----------------
// byte(b,k) = b*2048 + (k>>6)*64 + ((((k>>4)&3) ^ ((b>>1)&3))<<4) + (k&15)
__global__ void spikes_kernel(const float* __restrict__ x, uint8_t* __restrict__ strain) {
  int gid = blockIdx.x * 256 + threadIdx.x;   // over 256*2048/16 = 32768
  int b = gid >> 7, kg = gid & 127;
  const float* xp = x + (size_t)b * NN + kg * 16;
  float nsf[16], sp[16]; int ns[16];
#pragma unroll
  for (int e = 0; e < 16; ++e) {
    float nv = rintf(xp[e] * 32.0f);
    nsf[e] = nv; ns[e] = (int)nv; sp[e] = 32.0f / fmaxf(nv, 1.0f);
  }
  uint32_t dst = (uint32_t)b * 2048 + ((uint32_t)(kg >> 2) << 6)
               + ((uint32_t)((kg & 3) ^ ((b >> 1) & 3)) << 4);
  int cyc0 = blockIdx.y * 4;
#pragma unroll
  for (int i = 0; i < 4; ++i) {
    int cyc = cyc0 + i;
    float ct = (float)cyc;
    uint32_t w[4] = {0u, 0u, 0u, 0u};
#pragma unroll
    for (int e = 0; e < 16; ++e) {
      bool res;
      if (ns[e] == TSIM)      res = true;
      else if (ns[e] == 0)    res = false;
      else {
        float q = floorf(ct / sp[e]);
        float m = fmodf(ct, sp[e]);
        res = (q < nsf[e]) && (floorf(m) == 0.0f);
      }
      if (res) w[e >> 2] |= 1u << ((e & 3) * 8);
    }
    uint4 pk; pk.x = w[0]; pk.y = w[1]; pk.z = w[2]; pk.w = w[3];
    *(uint4*)(strain + (size_t)cyc * PLANE + dst) = pk;
  }
}

// ---------------- W split: exact i8 3-plane fixed point ----------------
__global__ __launch_bounds__(256) void wsplit_kernel(const float* __restrict__ W,
                                                     uint8_t* __restrict__ Whm) {
  __shared__ uint32_t lds[3 * 2048];
  int kk = blockIdx.x, nt = blockIdx.y, c = blockIdx.z;
  int tid = threadIdx.x, lane = tid & 63, wid = tid >> 6;
  const float* src = W + ((size_t)c * NN + (size_t)kk * 128) * NN + nt * 64 + lane;
#pragma unroll
  for (int kp = 0; kp < 8; ++kp) {
    uint32_t pk0 = 0, pk1 = 0, pk2 = 0;
#pragma unroll
    for (int q = 0; q < 4; ++q) {
      int kl = kp * 16 + wid * 4 + q;
      float w = src[(size_t)kl * NN];
      int wi = (int)rintf(w * 0x1p25f);
      int l8 = (int)(int8_t)(uint8_t)(wi & 0xFF);
      int r1 = (wi - l8) >> 8;
      int m8 = (int)(int8_t)(uint8_t)(r1 & 0xFF);
      int h8 = (r1 - m8) >> 8;
      pk0 |= ((uint32_t)(uint8_t)h8) << (q * 8);
      pk1 |= ((uint32_t)(uint8_t)m8) << (q * 8);
      pk2 |= ((uint32_t)(uint8_t)l8) << (q * 8);
    }
    int kq = kp * 4 + wid;
    lds[0 * 2048 + kq * 64 + lane] = pk0;
    lds[1 * 2048 + kq * 64 + lane] = pk1;
    lds[2 * 2048 + kq * 64 + lane] = pk2;
  }
  __syncthreads();
  size_t chunkbase = (((size_t)c * 32 + nt) * 16 + kk) * 24576;
#pragma unroll
  for (int g = 0; g < 6; ++g) {
    int idx = g * 256 + tid;
    int ks2 = (idx >= 768) ? 1 : 0;
    int rem = idx - ks2 * 768;
    int p = rem >> 8;
    int n = (rem >> 2) & 63;
    int s = rem & 3;
    int k16 = s ^ ((n >> 1) & 3);
    int kqb = ks2 * 16 + k16 * 4;
    uint4 v;
    v.x = lds[p * 2048 + (kqb + 0) * 64 + n];
    v.y = lds[p * 2048 + (kqb + 1) * 64 + n];
    v.z = lds[p * 2048 + (kqb + 2) * 64 + n];
    v.w = lds[p * 2048 + (kqb + 3) * 64 + n];
    *(uint4*)(Whm + chunkbase + (size_t)idx * 16) = v;
  }
}

// ---------------- quad-step skewed dispatch, 64-row blocks, 3 blocks/CU ----------------
// grid (active cores, 128): nt = y>>2, rq = y&3 (W-slice siblings adjacent).
// A reg-staged into single-buffer LDS (16K); B gload_lds double-buffer (24K). LDS 40K.
__global__ __launch_bounds__(512, 6) void step4_kernel(
    const uint8_t* __restrict__ Whm, const float* __restrict__ thresholds,
    const uint8_t* __restrict__ strain, uint8_t* bufs,
    float* __restrict__ memb, float* __restrict__ out, int j, int c_lo) {
  __shared__ uint8_t smem[40960];   // A: 4st x 4K = 16K (single) | B: 2buf x 12K = 24K

  const int tid = threadIdx.x;
  const int c = c_lo + blockIdx.x;
  const int yy = blockIdx.y;
  const int nt = yy >> 2, rq = yy & 3;
  const int sl = 4 * (j - c);                // local step base (0..28)
  const int l = tid & 63, wid = tid >> 6;
  const int wm = wid >> 2, wn = wid & 3;     // 32-row x 16-col wave tiles
  const int lr = l & 15, lh = l >> 4;

  // input planes for the 4 steps
  const uint8_t* pls[4];
#pragma unroll
  for (int st = 0; st < 4; ++st)
    pls[st] = (c == 0) ? strain + (size_t)(sl + st) * PLANE
                       : bufs + ((size_t)(c - 1) * 8 + ((sl + st) & 7)) * PLANE;

  // A sources: 2 reg-loads/thread; gi = j_*512+tid; si = gi>>8 (step), idx = gi&255
  const uint8_t* ab[2];
  uint32_t adst[2];
#pragma unroll
  for (int j_ = 0; j_ < 2; ++j_) {
    int gi = j_ * 512 + tid;
    int si = gi >> 8, idx = gi & 255;
    int row = idx >> 2, kq = idx & 3;
    ab[j_] = pls[si] + (size_t)(rq * 64 + row) * 2048 + kq * 16;
    adst[j_] = si * 4096 + idx * 16;
  }
  const uint8_t* wbase = Whm + (((size_t)c * 32 + nt) * 16) * 24576;
  uint8_t* Bs = smem + 16384;

  const uint32_t swz = (uint32_t)(lh ^ ((lr >> 1) & 3)) << 4;
  const uint32_t aoff = (uint32_t)(wm * 32 + lr) * 64 + swz;   // + st*4096 + mi*1024
  const uint32_t boff = (uint32_t)(wn * 16 + lr) * 64 + swz;   // + p*4096

  i4v acc[4][3][2];
  const i4v izero = {0, 0, 0, 0};
#pragma unroll
  for (int st = 0; st < 4; ++st)
#pragma unroll
    for (int p = 0; p < 3; ++p) { acc[st][p][0] = izero; acc[st][p][1] = izero; }

  i4v areg0, areg1;    // in-flight A chunk (reused every iter; WAR safe in-order)

  auto loadA = [&](int k) {
    areg0 = *(const i4v*)(ab[0] + k * 64);
    areg1 = *(const i4v*)(ab[1] + k * 64);
  };
  auto writeA = [&]() {
    *(i4v*)(smem + adst[0]) = areg0;
    *(i4v*)(smem + adst[1]) = areg1;
  };
  auto issueB = [&](int k, int slot) {
    const uint8_t* bs = wbase + (size_t)(k >> 1) * 24576 + (size_t)(k & 1) * 12288;
    uint8_t* Bd = Bs + slot * 12288;
    load_lds16(bs + tid * 16, Bd + tid * 16);
    if (tid < 256) load_lds16(bs + 8192 + tid * 16, Bd + 8192 + tid * 16);
  };

  auto comp = [&](int slot) {
    const uint8_t* Bb = Bs + slot * 12288;
    i4v bf0 = *(const i4v*)(Bb + 0 * 4096 + boff);
    i4v bf1 = *(const i4v*)(Bb + 1 * 4096 + boff);
    i4v bf2 = *(const i4v*)(Bb + 2 * 4096 + boff);
    __builtin_amdgcn_s_setprio(1);
#pragma unroll
    for (int st = 0; st < 4; ++st) {
      const uint8_t* Ab = smem + st * 4096;
#pragma unroll
      for (int mi = 0; mi < 2; ++mi) {
        i4v a_ = *(const i4v*)(Ab + aoff + mi * 1024);
        acc[st][0][mi] = __builtin_amdgcn_mfma_i32_16x16x64_i8(a_, bf0, acc[st][0][mi], 0, 0, 0);
        acc[st][1][mi] = __builtin_amdgcn_mfma_i32_16x16x64_i8(a_, bf1, acc[st][1][mi], 0, 0, 0);
        acc[st][2][mi] = __builtin_amdgcn_mfma_i32_16x16x64_i8(a_, bf2, acc[st][2][mi], 0, 0, 0);
      }
    }
    __builtin_amdgcn_s_setprio(0);
  };

#define WAITV(n) asm volatile("s_waitcnt vmcnt(" #n ")" ::: "memory")
#define WAITL() asm volatile("s_waitcnt lgkmcnt(0)" ::: "memory")
#define BAR() do { __builtin_amdgcn_s_barrier(); __builtin_amdgcn_sched_barrier(0); } while (0)

  loadA(0);            // A_0 -> regs (2 vmem)
  issueB(0, 0);        // B_0 -> LDS slot 0 (nB vmem, issued after A_0)
  for (int k = 0; k < 32; ++k) {
    // retire A_k regs (B_k may still fly: nB outstanding allowed)
    if (wid < 4) { WAITV(2); } else { WAITV(1); }
    BAR();                               // A_lds + B slot (k+1)&1 free (comp(k-1) done)
    writeA();                            // ds_write A_k
    if (k < 31) {
      loadA(k + 1);                      // A_{k+1} -> regs
      issueB(k + 1, (k + 1) & 1);        // B_{k+1} -> other slot
      if (wid < 4) { WAITV(4); } else { WAITV(3); }   // retire B_k
    } else {
      WAITV(0);
    }
    WAITL();                             // ds_write visible
    BAR();                               // chunk k fully staged for all waves
    comp(k & 1);
    WAITL();                             // this wave's ds_reads of chunk k complete
  }
#undef WAITV
#undef WAITL
#undef BAR

  // ---- epilogue: 4 sequential transposes, then single memb RMW with 4 ordered fires ----
  const float thr = thresholds[c];
  float* Cl = (float*)smem;                  // [64][68] f32 = 17408 B
  float4 d[4][2];
#pragma unroll
  for (int st = 0; st < 4; ++st) {
    __syncthreads();
#pragma unroll
    for (int mi = 0; mi < 2; ++mi)
#pragma unroll
      for (int rg = 0; rg < 4; ++rg) {
        int row = wm * 32 + mi * 16 + lh * 4 + rg;
        int col = wn * 16 + lr;
        int di = (acc[st][0][mi][rg] << 16) + (acc[st][1][mi][rg] << 8) + acc[st][2][mi][rg];
        Cl[row * 68 + col] = (float)di * 0x1p-25f;   // single RNE rounding of exact sum
      }
    __syncthreads();
#pragma unroll
    for (int p = 0; p < 2; ++p) {
      int rr = p * 32 + (tid >> 4);
      int c4 = (tid & 15) * 4;
      d[st][p] = *(const float4*)&Cl[rr * 68 + c4];
    }
  }

  float* membp = memb + (size_t)c * PLANE;
  uint8_t* bps[4];
#pragma unroll
  for (int st = 0; st < 4; ++st)
    bps[st] = bufs + ((size_t)c * 8 + ((sl + st) & 7)) * PLANE;
  const bool last = (j == 14);
#pragma unroll
  for (int p = 0; p < 2; ++p) {
    int rr = p * 32 + (tid >> 4);
    int c4 = (tid & 15) * 4;
    int b = rq * 64 + rr;
    int o = nt * 64 + c4;
    size_t idx = (size_t)b * NN + o;
    float4 mv;
    if (j == c) mv = make_float4(0.f, 0.f, 0.f, 0.f);   // first active dispatch: memb = 0
    else        mv = *(float4*)(membp + idx);
    float4 cv;
    if (c == 7) {
      if (j == 7) cv = make_float4(0.f, 0.f, 0.f, 0.f); // first counting dispatch
      else        cv = *(float4*)(out + idx);
    }
    uint32_t ba = (uint32_t)b * 2048 + ((uint32_t)(o >> 6) << 6)
                + ((uint32_t)(((o >> 4) & 3) ^ ((b >> 1) & 3)) << 4) + (o & 15);
#pragma unroll
    for (int st = 0; st < 4; ++st) {
      mv.x += d[st][p].x; mv.y += d[st][p].y; mv.z += d[st][p].z; mv.w += d[st][p].w;
      bool fx = thr < mv.x, fy = thr < mv.y, fz = thr < mv.z, fw = thr < mv.w;
      if (fx) mv.x -= thr;  if (fy) mv.y -= thr;
      if (fz) mv.z -= thr;  if (fw) mv.w -= thr;
      if (c < 7) {
        uchar4 pk;
        pk.x = fx ? 1 : 0; pk.y = fy ? 1 : 0; pk.z = fz ? 1 : 0; pk.w = fw ? 1 : 0;
        *(uchar4*)(bps[st] + ba) = pk;
      } else {
        cv.x += fx ? 1.f : 0.f; cv.y += fy ? 1.f : 0.f;
        cv.z += fz ? 1.f : 0.f; cv.w += fw ? 1.f : 0.f;
      }
    }
    *(float4*)(membp + idx) = mv;
    if (c == 7) {
      if (last) { cv.x *= 0x1p-5f; cv.y *= 0x1p-5f; cv.z *= 0x1p-5f; cv.w *= 0x1p-5f; }
      *(float4*)(out + idx) = cv;
    }
  }
}

extern "C" void kernel_launch(void* const* d_in, const int* in_sizes, int n_in,
                              void* d_out, int out_size, void* d_ws, size_t ws_size,
                              hipStream_t stream) {
  const float* x   = (const float*)d_in[0];
  const float* W   = (const float*)d_in[1];
  const float* thr = (const float*)d_in[2];
  float* out = (float*)d_out;
  uint8_t* ws = (uint8_t*)d_ws;

  // layout: memb f32 16.78M | strain 16.78M | bufs 7x8 planes 29.36M | Whm 100.66M
  float*   memb   = (float*)ws;
  uint8_t* strain = ws + 16777216;
  uint8_t* bufs   = ws + 33554432;
  uint8_t* Whm    = ws + 62914560;

  spikes_kernel<<<dim3(128, 8), 256, 0, stream>>>(x, strain);
  wsplit_kernel<<<dim3(16, 32, 8), 256, 0, stream>>>(W, Whm);

  for (int j = 0; j < 15; ++j) {      // core c does local steps 4(j-c)..+3, active for c<=j<=c+7
    int c_lo = (j > 7) ? (j - 7) : 0;
    int c_hi = (j < 7) ? j : 7;
    step4_kernel<<<dim3(c_hi - c_lo + 1, 128), 512, 0, stream>>>(
        Whm, thr, strain, bufs, memb, out, j, c_lo);
  }
}

// Round 18
// 814.228 us; speedup vs baseline: 11.8648x; 11.8648x over previous
//
#include <hip/hip_runtime.h>
#include <stdint.h>

#define NN 2048
#define NCORE 8
#define TSIM 32
#define PLANE (256*2048)       // 512 KiB i8 plane

typedef int i4v __attribute__((ext_vector_type(4)));

__device__ __forceinline__ void load_lds16(const void* g, void* l) {
  __builtin_amdgcn_global_load_lds((const __attribute__((address_space(1))) void*)g,
                                   (__attribute__((address_space(3))) void*)l, 16, 0, 0);
}

// ---------------- spike trains, i8 {0,1}, 64B-group 2-bit swizzle ----------------
// byte(b,k) = b*2048 + (k>>6)*64 + ((((k>>4)&3) ^ ((b>>1)&3))<<4) + (k&15)
__global__ void spikes_kernel(const float* __restrict__ x, uint8_t* __restrict__ strain) {
  int gid = blockIdx.x * 256 + threadIdx.x;   // over 256*2048/16 = 32768
  int b = gid >> 7, kg = gid & 127;
  const float* xp = x + (size_t)b * NN + kg * 16;
  float nsf[16], sp[16]; int ns[16];
#pragma unroll
  for (int e = 0; e < 16; ++e) {
    float nv = rintf(xp[e] * 32.0f);
    nsf[e] = nv; ns[e] = (int)nv; sp[e] = 32.0f / fmaxf(nv, 1.0f);
  }
  uint32_t dst = (uint32_t)b * 2048 + ((uint32_t)(kg >> 2) << 6)
               + ((uint32_t)((kg & 3) ^ ((b >> 1) & 3)) << 4);
  int cyc0 = blockIdx.y * 4;
#pragma unroll
  for (int i = 0; i < 4; ++i) {
    int cyc = cyc0 + i;
    float ct = (float)cyc;
    uint32_t w[4] = {0u, 0u, 0u, 0u};
#pragma unroll
    for (int e = 0; e < 16; ++e) {
      bool res;
      if (ns[e] == TSIM)      res = true;
      else if (ns[e] == 0)    res = false;
      else {
        float q = floorf(ct / sp[e]);
        float m = fmodf(ct, sp[e]);
        res = (q < nsf[e]) && (floorf(m) == 0.0f);
      }
      if (res) w[e >> 2] |= 1u << ((e & 3) * 8);
    }
    uint4 pk; pk.x = w[0]; pk.y = w[1]; pk.z = w[2]; pk.w = w[3];
    *(uint4*)(strain + (size_t)cyc * PLANE + dst) = pk;
  }
}

// ---------------- W split: exact i8 3-plane fixed point ----------------
__global__ __launch_bounds__(256) void wsplit_kernel(const float* __restrict__ W,
                                                     uint8_t* __restrict__ Whm) {
  __shared__ uint32_t lds[3 * 2048];
  int kk = blockIdx.x, nt = blockIdx.y, c = blockIdx.z;
  int tid = threadIdx.x, lane = tid & 63, wid = tid >> 6;
  const float* src = W + ((size_t)c * NN + (size_t)kk * 128) * NN + nt * 64 + lane;
#pragma unroll
  for (int kp = 0; kp < 8; ++kp) {
    uint32_t pk0 = 0, pk1 = 0, pk2 = 0;
#pragma unroll
    for (int q = 0; q < 4; ++q) {
      int kl = kp * 16 + wid * 4 + q;
      float w = src[(size_t)kl * NN];
      int wi = (int)rintf(w * 0x1p25f);
      int l8 = (int)(int8_t)(uint8_t)(wi & 0xFF);
      int r1 = (wi - l8) >> 8;
      int m8 = (int)(int8_t)(uint8_t)(r1 & 0xFF);
      int h8 = (r1 - m8) >> 8;
      pk0 |= ((uint32_t)(uint8_t)h8) << (q * 8);
      pk1 |= ((uint32_t)(uint8_t)m8) << (q * 8);
      pk2 |= ((uint32_t)(uint8_t)l8) << (q * 8);
    }
    int kq = kp * 4 + wid;
    lds[0 * 2048 + kq * 64 + lane] = pk0;
    lds[1 * 2048 + kq * 64 + lane] = pk1;
    lds[2 * 2048 + kq * 64 + lane] = pk2;
  }
  __syncthreads();
  size_t chunkbase = (((size_t)c * 32 + nt) * 16 + kk) * 24576;
#pragma unroll
  for (int g = 0; g < 6; ++g) {
    int idx = g * 256 + tid;
    int ks2 = (idx >= 768) ? 1 : 0;
    int rem = idx - ks2 * 768;
    int p = rem >> 8;
    int n = (rem >> 2) & 63;
    int s = rem & 3;
    int k16 = s ^ ((n >> 1) & 3);
    int kqb = ks2 * 16 + k16 * 4;
    uint4 v;
    v.x = lds[p * 2048 + (kqb + 0) * 64 + n];
    v.y = lds[p * 2048 + (kqb + 1) * 64 + n];
    v.z = lds[p * 2048 + (kqb + 2) * 64 + n];
    v.w = lds[p * 2048 + (kqb + 3) * 64 + n];
    *(uint4*)(Whm + chunkbase + (size_t)idx * 16) = v;
  }
}

// ---------------- quad-step skewed dispatch: core c does local steps 4(j-c)..+3 ----------------
// grid (active cores, 128): nt = y>>2, rq = y&3 (W-slice siblings adjacent: fetch-once).
__global__ __launch_bounds__(512, 4) void step4_kernel(
    const uint8_t* __restrict__ Whm, const float* __restrict__ thresholds,
    const uint8_t* __restrict__ strain, uint8_t* bufs,
    float* __restrict__ memb, float* __restrict__ out, int j, int c_lo) {
  __shared__ uint8_t smem[57344];   // A: 4st x 2buf x 4K | B: 2buf x 12K; epilogue [64][68] f32

  const int tid = threadIdx.x;
  const int c = c_lo + blockIdx.x;
  const int yy = blockIdx.y;
  const int nt = yy >> 2, rq = yy & 3;
  const int sl = 4 * (j - c);                // local step base (0..28)
  const int l = tid & 63, wid = tid >> 6;
  const int wm = wid >> 2, wn = wid & 3;     // 32-row x 16-col wave tiles
  const int lr = l & 15, lh = l >> 4;

  // input planes for the 4 steps
  const uint8_t* pls[4];
#pragma unroll
  for (int st = 0; st < 4; ++st)
    pls[st] = (c == 0) ? strain + (size_t)(sl + st) * PLANE
                       : bufs + ((size_t)(c - 1) * 8 + ((sl + st) & 7)) * PLANE;

  // per-thread A DMA sources: 2 loads, gi = j_*512+tid; si = gi>>8, idx = gi&255
  const uint8_t* ab[2];
  uint32_t adst[2];
#pragma unroll
  for (int j_ = 0; j_ < 2; ++j_) {
    int gi = j_ * 512 + tid;
    int si = gi >> 8, idx = gi & 255;
    int row = idx >> 2, kq = idx & 3;
    ab[j_] = pls[si] + (size_t)(rq * 64 + row) * 2048 + kq * 16;
    adst[j_] = si * 8192 + idx * 16;        // + slot*4096
  }
  const uint8_t* wbase = Whm + (((size_t)c * 32 + nt) * 16) * 24576;
  uint8_t* Bs = smem + 32768;

  const uint32_t swz = (uint32_t)(lh ^ ((lr >> 1) & 3)) << 4;
  const uint32_t aoff = (uint32_t)(wm * 32 + lr) * 64 + swz;   // + st*8192 + slot*4096 + mi*1024
  const uint32_t boff = (uint32_t)(wn * 16 + lr) * 64 + swz;   // + p*4096

  i4v acc[4][3][2];
  const i4v izero = {0, 0, 0, 0};
#pragma unroll
  for (int st = 0; st < 4; ++st)
#pragma unroll
    for (int p = 0; p < 3; ++p) { acc[st][p][0] = izero; acc[st][p][1] = izero; }

  auto issue = [&](int k, int slot) {
#pragma unroll
    for (int j_ = 0; j_ < 2; ++j_)
      load_lds16(ab[j_] + k * 64, smem + adst[j_] + slot * 4096);
    const uint8_t* bs = wbase + (size_t)(k >> 1) * 24576 + (size_t)(k & 1) * 12288;
    uint8_t* Bd = Bs + slot * 12288;
    load_lds16(bs + tid * 16, Bd + tid * 16);
    if (tid < 256) load_lds16(bs + 8192 + tid * 16, Bd + 8192 + tid * 16);
  };

  auto comp = [&](int slot) {
    const uint8_t* Bb = Bs + slot * 12288;
    i4v bf0 = *(const i4v*)(Bb + 0 * 4096 + boff);
    i4v bf1 = *(const i4v*)(Bb + 1 * 4096 + boff);
    i4v bf2 = *(const i4v*)(Bb + 2 * 4096 + boff);
    __builtin_amdgcn_s_setprio(1);
#pragma unroll
    for (int st = 0; st < 4; ++st) {
      const uint8_t* Ab = smem + st * 8192 + slot * 4096;
#pragma unroll
      for (int mi = 0; mi < 2; ++mi) {
        i4v a_ = *(const i4v*)(Ab + aoff + mi * 1024);
        acc[st][0][mi] = __builtin_amdgcn_mfma_i32_16x16x64_i8(a_, bf0, acc[st][0][mi], 0, 0, 0);
        acc[st][1][mi] = __builtin_amdgcn_mfma_i32_16x16x64_i8(a_, bf1, acc[st][1][mi], 0, 0, 0);
        acc[st][2][mi] = __builtin_amdgcn_mfma_i32_16x16x64_i8(a_, bf2, acc[st][2][mi], 0, 0, 0);
      }
    }
    __builtin_amdgcn_s_setprio(0);
  };

#define WAITV(n) asm volatile("s_waitcnt vmcnt(" #n ")" ::: "memory")
#define WAITL() asm volatile("s_waitcnt lgkmcnt(0)" ::: "memory")
#define BAR() do { __builtin_amdgcn_s_barrier(); __builtin_amdgcn_sched_barrier(0); } while (0)

  issue(0, 0);
  for (int k = 0; k < 32; ++k) {
    if (k < 31) {
      issue(k + 1, (k + 1) & 1);
      if (tid < 256) { WAITV(4); } else { WAITV(3); }
    } else {
      WAITV(0);
    }
    BAR();
    comp(k & 1);
    WAITL();
    BAR();
  }
#undef WAITV
#undef WAITL
#undef BAR

  // ---- epilogue: 4 sequential transposes, then single memb RMW with 4 ordered fires ----
  const float thr = thresholds[c];
  float* Cl = (float*)smem;                  // [64][68] f32 = 17408 B
  float4 d[4][2];
#pragma unroll
  for (int st = 0; st < 4; ++st) {
    __syncthreads();
#pragma unroll
    for (int mi = 0; mi < 2; ++mi)
#pragma unroll
      for (int rg = 0; rg < 4; ++rg) {
        int row = wm * 32 + mi * 16 + lh * 4 + rg;
        int col = wn * 16 + lr;
        int di = (acc[st][0][mi][rg] << 16) + (acc[st][1][mi][rg] << 8) + acc[st][2][mi][rg];
        Cl[row * 68 + col] = (float)di * 0x1p-25f;   // single RNE rounding of exact sum
      }
    __syncthreads();
#pragma unroll
    for (int p = 0; p < 2; ++p) {
      int rr = p * 32 + (tid >> 4);
      int c4 = (tid & 15) * 4;
      d[st][p] = *(const float4*)&Cl[rr * 68 + c4];
    }
  }

  float* membp = memb + (size_t)c * PLANE;
  uint8_t* bps[4];
#pragma unroll
  for (int st = 0; st < 4; ++st)
    bps[st] = bufs + ((size_t)c * 8 + ((sl + st) & 7)) * PLANE;
  const bool last = (j == 14);
#pragma unroll
  for (int p = 0; p < 2; ++p) {
    int rr = p * 32 + (tid >> 4);
    int c4 = (tid & 15) * 4;
    int b = rq * 64 + rr;
    int o = nt * 64 + c4;
    size_t idx = (size_t)b * NN + o;
    float4 mv;
    if (j == c) mv = make_float4(0.f, 0.f, 0.f, 0.f);   // first active dispatch: memb = 0
    else        mv = *(float4*)(membp + idx);
    float4 cv;
    if (c == 7) {
      if (j == 7) cv = make_float4(0.f, 0.f, 0.f, 0.f); // first counting dispatch
      else        cv = *(float4*)(out + idx);
    }
    uint32_t ba = (uint32_t)b * 2048 + ((uint32_t)(o >> 6) << 6)
                + ((uint32_t)(((o >> 4) & 3) ^ ((b >> 1) & 3)) << 4) + (o & 15);
#pragma unroll
    for (int st = 0; st < 4; ++st) {
      mv.x += d[st][p].x; mv.y += d[st][p].y; mv.z += d[st][p].z; mv.w += d[st][p].w;
      bool fx = thr < mv.x, fy = thr < mv.y, fz = thr < mv.z, fw = thr < mv.w;
      if (fx) mv.x -= thr;  if (fy) mv.y -= thr;
      if (fz) mv.z -= thr;  if (fw) mv.w -= thr;
      if (c < 7) {
        uchar4 pk;
        pk.x = fx ? 1 : 0; pk.y = fy ? 1 : 0; pk.z = fz ? 1 : 0; pk.w = fw ? 1 : 0;
        *(uchar4*)(bps[st] + ba) = pk;
      } else {
        cv.x += fx ? 1.f : 0.f; cv.y += fy ? 1.f : 0.f;
        cv.z += fz ? 1.f : 0.f; cv.w += fw ? 1.f : 0.f;
      }
    }
    *(float4*)(membp + idx) = mv;
    if (c == 7) {
      if (last) { cv.x *= 0x1p-5f; cv.y *= 0x1p-5f; cv.z *= 0x1p-5f; cv.w *= 0x1p-5f; }
      *(float4*)(out + idx) = cv;
    }
  }
}

extern "C" void kernel_launch(void* const* d_in, const int* in_sizes, int n_in,
                              void* d_out, int out_size, void* d_ws, size_t ws_size,
                              hipStream_t stream) {
  const float* x   = (const float*)d_in[0];
  const float* W   = (const float*)d_in[1];
  const float* thr = (const float*)d_in[2];
  float* out = (float*)d_out;
  uint8_t* ws = (uint8_t*)d_ws;

  // layout: memb f32 16.78M | strain 16.78M | bufs 7x8 planes 29.36M | Whm 100.66M
  float*   memb   = (float*)ws;
  uint8_t* strain = ws + 16777216;
  uint8_t* bufs   = ws + 33554432;
  uint8_t* Whm    = ws + 62914560;

  spikes_kernel<<<dim3(128, 8), 256, 0, stream>>>(x, strain);
  wsplit_kernel<<<dim3(16, 32, 8), 256, 0, stream>>>(W, Whm);

  for (int j = 0; j < 15; ++j) {      // core c does local steps 4(j-c)..+3, active for c<=j<=c+7
    int c_lo = (j > 7) ? (j - 7) : 0;
    int c_hi = (j < 7) ? j : 7;
    step4_kernel<<<dim3(c_hi - c_lo + 1, 128), 512, 0, stream>>>(
        Whm, thr, strain, bufs, memb, out, j, c_lo);
  }
}